// Round 4
// baseline (225.175 us; speedup 1.0000x reference)
//
#include <hip/hip_runtime.h>
#include <hip/hip_bf16.h>
#include <stdint.h>
#include <math.h>

#define S_LEN   4096
#define D_MODEL 1024
#define NHEAD   16
#define DK      64

typedef __attribute__((ext_vector_type(8))) __bf16 bf16x8;
typedef __attribute__((ext_vector_type(4))) float  f32x4;
using bf16 = __hip_bfloat16;

__device__ __forceinline__ void load_lds16(const bf16* g, bf16* l) {
    __builtin_amdgcn_global_load_lds(
        (const __attribute__((address_space(1))) void*)g,
        (__attribute__((address_space(3))) void*)l, 16, 0, 0);
}

// ---------------- fused fp32 -> bf16 convert (x + 4 weights), 4 elems/thread ----------------
__global__ void cvt_all(const float* __restrict__ x,
                        const float* __restrict__ w0, const float* __restrict__ w1,
                        const float* __restrict__ w2, const float* __restrict__ w3,
                        bf16* __restrict__ xb,
                        bf16* __restrict__ b0, bf16* __restrict__ b1,
                        bf16* __restrict__ b2, bf16* __restrict__ b3)
{
    size_t i4 = ((size_t)blockIdx.x * 256 + threadIdx.x) * 4;
    const float* s; bf16* d; size_t off;
    const size_t NX = (size_t)S_LEN * D_MODEL;         // 4M
    const size_t NW = (size_t)D_MODEL * D_MODEL;       // 1M
    if (i4 < NX) { s = x; d = xb; off = i4; }
    else {
        size_t j = i4 - NX;
        int sel = (int)(j >> 20);
        off = j & (NW - 1);
        s = sel == 0 ? w0 : sel == 1 ? w1 : sel == 2 ? w2 : w3;
        d = sel == 0 ? b0 : sel == 1 ? b1 : sel == 2 ? b2 : b3;
    }
    float4 v = *(const float4*)&s[off];
    bf16 t[4] __attribute__((aligned(8)));
    t[0] = __float2bfloat16(v.x); t[1] = __float2bfloat16(v.y);
    t[2] = __float2bfloat16(v.z); t[3] = __float2bfloat16(v.w);
    *(uint64_t*)&d[off] = *(const uint64_t*)t;
}

// ---------------- QKV GEMM: C = Xb (4096x1024) * W^T ----------------
// z = 0 -> Qf (fp32), 1 -> Kf (fp32), 2 -> VtG (bf16, transposed [D][S])
__global__ __launch_bounds__(256) void qkv_gemm(
    const bf16* __restrict__ Xb,
    const bf16* __restrict__ Wq, const bf16* __restrict__ Wk, const bf16* __restrict__ Wv,
    float* __restrict__ Qf, float* __restrict__ Kf, bf16* __restrict__ VtG)
{
    const int K = D_MODEL, N = D_MODEL;
    int z = blockIdx.z;
    const bf16* B = (z == 0) ? Wq : (z == 1) ? Wk : Wv;

    __shared__ __align__(16) bf16 As[2][128 * 32];
    __shared__ __align__(16) bf16 Bs[2][128 * 32];
    __shared__ __align__(16) bf16 Ts[4][64 * 24];   // per-wave V-transpose strip

    int row0 = blockIdx.y * 128;
    int col0 = blockIdx.x * 128;
    int tid  = threadIdx.x;
    int wv   = tid >> 6, lane = tid & 63;
    int m16  = lane & 15, quad = lane >> 4;
    int wr   = (wv >> 1) * 64, wc = (wv & 1) * 64;
    int l4   = lane >> 2, l3 = (lane & 3) * 8;

    const bf16* ga_base = Xb + (size_t)(row0 + wv * 16 + l4) * K + l3;
    const bf16* gb_base = B  + (size_t)(col0 + wv * 16 + l4) * K + l3;

    auto stage = [&](int k0, int buf) {
        load_lds16(ga_base + k0,            &As[buf][wv * 512]);
        load_lds16(ga_base + k0 + 64 * K,   &As[buf][2048 + wv * 512]);
        load_lds16(gb_base + k0,            &Bs[buf][wv * 512]);
        load_lds16(gb_base + k0 + 64 * K,   &Bs[buf][2048 + wv * 512]);
    };

    f32x4 acc[4][4];
    #pragma unroll
    for (int i = 0; i < 4; i++)
        #pragma unroll
        for (int j = 0; j < 4; j++) acc[i][j] = (f32x4){0.f, 0.f, 0.f, 0.f};

    stage(0, 0);
    for (int k0 = 0; k0 < K; k0 += 32) {
        __syncthreads();
        int buf = (k0 >> 5) & 1;
        if (k0 + 32 < K) stage(k0 + 32, buf ^ 1);
        bf16x8 a[4], b[4];
        #pragma unroll
        for (int mi = 0; mi < 4; mi++) a[mi] = *(const bf16x8*)&As[buf][(wr + mi * 16 + m16) * 32 + quad * 8];
        #pragma unroll
        for (int ni = 0; ni < 4; ni++) b[ni] = *(const bf16x8*)&Bs[buf][(wc + ni * 16 + m16) * 32 + quad * 8];
        #pragma unroll
        for (int mi = 0; mi < 4; mi++)
            #pragma unroll
            for (int ni = 0; ni < 4; ni++)
                acc[mi][ni] = __builtin_amdgcn_mfma_f32_16x16x32_bf16(a[mi], b[ni], acc[mi][ni], 0, 0, 0);
    }

    if (z < 2) {
        float* O = (z == 0) ? Qf : Kf;
        #pragma unroll
        for (int mi = 0; mi < 4; mi++)
            #pragma unroll
            for (int ni = 0; ni < 4; ni++)
                #pragma unroll
                for (int r = 0; r < 4; r++) {
                    int gr = row0 + wr + mi * 16 + quad * 4 + r;
                    int gc = col0 + wc + ni * 16 + m16;
                    O[(size_t)gr * N + gc] = acc[mi][ni][r];
                }
    } else {
        // per-wave transpose through LDS, then coalesced 16B stores to VtG[gc][gr]
        #pragma unroll
        for (int mi = 0; mi < 4; mi++) {
            #pragma unroll
            for (int nt = 0; nt < 4; nt++) {
                bf16 t4[4] __attribute__((aligned(8)));
                #pragma unroll
                for (int r = 0; r < 4; r++) t4[r] = __float2bfloat16(acc[mi][nt][r]);
                *(uint64_t*)&Ts[wv][(nt * 16 + m16) * 24 + quad * 4] = *(const uint64_t*)t4;
            }
            #pragma unroll
            for (int rep = 0; rep < 2; rep++) {
                int c  = (lane >> 1) + rep * 32;
                int r8 = lane & 1;
                bf16x8 val = *(const bf16x8*)&Ts[wv][c * 24 + r8 * 8];
                int gc = col0 + wc + c;
                int gr = row0 + wr + mi * 16 + r8 * 8;
                *(bf16x8*)&VtG[(size_t)gc * S_LEN + gr] = val;
            }
        }
    }
}

// ---------------- Output GEMM: out = Attn(bf16) * Wo^T -> fp32 ----------------
__global__ __launch_bounds__(256) void out_gemm(
    const bf16* __restrict__ A_, const bf16* __restrict__ B,
    float* __restrict__ C)
{
    const int K = D_MODEL, N = D_MODEL;
    __shared__ __align__(16) bf16 As[2][128 * 32];
    __shared__ __align__(16) bf16 Bs[2][128 * 32];

    int row0 = blockIdx.y * 128;
    int col0 = blockIdx.x * 128;
    int tid  = threadIdx.x;
    int wv   = tid >> 6, lane = tid & 63;
    int m16  = lane & 15, quad = lane >> 4;
    int wr   = (wv >> 1) * 64, wc = (wv & 1) * 64;
    int l4   = lane >> 2, l3 = (lane & 3) * 8;

    const bf16* ga_base = A_ + (size_t)(row0 + wv * 16 + l4) * K + l3;
    const bf16* gb_base = B  + (size_t)(col0 + wv * 16 + l4) * K + l3;

    auto stage = [&](int k0, int buf) {
        load_lds16(ga_base + k0,            &As[buf][wv * 512]);
        load_lds16(ga_base + k0 + 64 * K,   &As[buf][2048 + wv * 512]);
        load_lds16(gb_base + k0,            &Bs[buf][wv * 512]);
        load_lds16(gb_base + k0 + 64 * K,   &Bs[buf][2048 + wv * 512]);
    };

    f32x4 acc[4][4];
    #pragma unroll
    for (int i = 0; i < 4; i++)
        #pragma unroll
        for (int j = 0; j < 4; j++) acc[i][j] = (f32x4){0.f, 0.f, 0.f, 0.f};

    stage(0, 0);
    for (int k0 = 0; k0 < K; k0 += 32) {
        __syncthreads();
        int buf = (k0 >> 5) & 1;
        if (k0 + 32 < K) stage(k0 + 32, buf ^ 1);
        bf16x8 a[4], b[4];
        #pragma unroll
        for (int mi = 0; mi < 4; mi++) a[mi] = *(const bf16x8*)&As[buf][(wr + mi * 16 + m16) * 32 + quad * 8];
        #pragma unroll
        for (int ni = 0; ni < 4; ni++) b[ni] = *(const bf16x8*)&Bs[buf][(wc + ni * 16 + m16) * 32 + quad * 8];
        #pragma unroll
        for (int mi = 0; mi < 4; mi++)
            #pragma unroll
            for (int ni = 0; ni < 4; ni++)
                acc[mi][ni] = __builtin_amdgcn_mfma_f32_16x16x32_bf16(a[mi], b[ni], acc[mi][ni], 0, 0, 0);
    }

    #pragma unroll
    for (int mi = 0; mi < 4; mi++)
        #pragma unroll
        for (int ni = 0; ni < 4; ni++)
            #pragma unroll
            for (int r = 0; r < 4; r++) {
                int gr = row0 + wr + mi * 16 + quad * 4 + r;
                int gc = col0 + wc + ni * 16 + m16;
                C[(size_t)gr * N + gc] = acc[mi][ni][r];
            }
}

// ---------------- RoPE (fp32 in, bf16 out) ----------------
// Folds (1/sqrt(dk)) * log2(e) into Q so attention can use exp2 directly
// (softmax over s*log2e in base 2 == softmax over s in base e, exactly).
__global__ void rope_kernel(const float* __restrict__ Qf, const float* __restrict__ Kf,
                            const int* __restrict__ pos,
                            bf16* __restrict__ Qb, bf16* __restrict__ Kb)
{
    int gid = blockIdx.x * 256 + threadIdx.x;
    size_t i8 = (size_t)gid * 8;
    int s   = (int)(i8 >> 10);
    int col = (int)(i8 & 1023);
    int pair0 = (col & 63) >> 1;          // 0..31, multiple of 4
    float p = (float)pos[s];

    float4 qa = *(const float4*)&Qf[i8];
    float4 qb_ = *(const float4*)&Qf[i8 + 4];
    float4 ka = *(const float4*)&Kf[i8];
    float4 kb_ = *(const float4*)&Kf[i8 + 4];
    float q[8] = {qa.x, qa.y, qa.z, qa.w, qb_.x, qb_.y, qb_.z, qb_.w};
    float k[8] = {ka.x, ka.y, ka.z, ka.w, kb_.x, kb_.y, kb_.z, kb_.w};

    bf16 oq[8] __attribute__((aligned(16)));
    bf16 ok[8] __attribute__((aligned(16)));
    const float scale = 0.18033688011112042f;   // (1/sqrt(64)) * log2(e)
    #pragma unroll
    for (int j = 0; j < 4; j++) {
        float fi = (float)(pair0 + j);
        // inv_freq = 10000^(-fi/32) = exp2(-fi * log2(10000)/32)
        float inv = exp2f(fi * (-0.41524101186092028f));
        float ang = p * inv;
        float sn, cs;
        __sincosf(ang, &sn, &cs);
        float q1 = q[2 * j], q2 = q[2 * j + 1];
        float k1 = k[2 * j], k2 = k[2 * j + 1];
        oq[2 * j]     = __float2bfloat16((q1 * cs - q2 * sn) * scale);
        oq[2 * j + 1] = __float2bfloat16((q1 * sn + q2 * cs) * scale);
        ok[2 * j]     = __float2bfloat16(k1 * cs - k2 * sn);
        ok[2 * j + 1] = __float2bfloat16(k1 * sn + k2 * cs);
    }
    *(bf16x8*)&Qb[i8] = *(const bf16x8*)oq;
    *(bf16x8*)&Kb[i8] = *(const bf16x8*)ok;
}

// ---------------- Flash attention: VALU-reduced softmax ----------------
// Round-3 geometry (1024 blocks x 4 waves, 64-row q-tiles, 40960 B LDS ->
// 4 blocks/CU) + three VALU cuts (kernel was VALU-throughput-bound at
// VALUBusy 40% / MfmaUtil 19.5%):
//  1. exp2 instead of exp: log2(e) folded into RoPE Q-scale, so
//     p = exp2(s2 - 8) is a single v_exp_f32 (kills 16 v_mul/iter).
//  2. row sums on the MATRIX pipe: o_sum = mfma(P_frag, ones, o_sum)
//     (2 MFMA/iter replace 16 v_add/iter; epilogue shuffles eliminated —
//     o_sum[r] IS the row sum in C-layout, same rows as o[dt][r]).
//  3. s_setprio(1) around the contiguous 10-MFMA PV cluster (T5).
__global__ __launch_bounds__(256, 4) void attn_kernel(
    const bf16* __restrict__ Qb, const bf16* __restrict__ Kb, const bf16* __restrict__ VtG,
    bf16* __restrict__ Attn)
{
    int bx  = blockIdx.x;
    int h   = bx & 15;
    int qt  = 63 - (bx >> 4);            // longest q-tiles first
    int tid = threadIdx.x;
    int wv  = tid >> 6, lane = tid & 63;
    int m16 = lane & 15, quad = lane >> 4;
    int csw   = (lane & 3) ^ ((lane >> 3) & 3);     // staging column permutation
    int colsw = ((quad ^ ((m16 >> 1) & 3)) << 3);   // matching read-side XOR (elements)
    int psw   = (m16 & 7) ^ ((m16 >> 3) & 1);       // Ps chunk swizzle for this row
    int hc  = h * DK;
    int q0  = qt * 64;

    __shared__ __align__(16) bf16 KT[2][2][64 * 32];  // [buf][d-half][key*32 + d(swz)]   16 KB
    __shared__ __align__(16) bf16 VT[2][2][64 * 32];  // [buf][key-half][d*32 + key(swz)] 16 KB
    __shared__ __align__(16) bf16 Ps[64 * 64];        // XOR-swizzled P                    8 KB

    // staging: 256 threads cover a full 64x32 half-tile per load (1 op each)
    const bf16* kgl = Kb  + (size_t)(wv * 16 + (lane >> 2)) * D_MODEL + hc + csw * 8;
    const bf16* vgl = VtG + (size_t)(hc + wv * 16 + (lane >> 2)) * S_LEN + csw * 8;

    auto stage = [&](int kb, int buf) {
        size_t ko = (size_t)kb * 64;
        load_lds16(kgl + ko * D_MODEL,       &KT[buf][0][wv * 512]);
        load_lds16(kgl + ko * D_MODEL + 32,  &KT[buf][1][wv * 512]);
        load_lds16(vgl + ko,                 &VT[buf][0][wv * 512]);
        load_lds16(vgl + ko + 32,            &VT[buf][1][wv * 512]);
    };

    // Q fragment for this wave's 16 rows, in registers for the whole loop
    const bf16* qp = Qb + (size_t)(q0 + wv * 16 + m16) * D_MODEL + hc;
    bf16x8 aq0 = *(const bf16x8*)&qp[quad * 8];
    bf16x8 aq1 = *(const bf16x8*)&qp[32 + quad * 8];

    // constant all-ones B fragment for the row-sum MFMA
    bf16x8 bone;
    #pragma unroll
    for (int j = 0; j < 8; j++) bone[j] = (__bf16)1.0f;

    f32x4 o[4];
    f32x4 o_sum = (f32x4){0.f, 0.f, 0.f, 0.f};
    #pragma unroll
    for (int dt = 0; dt < 4; dt++) o[dt] = (f32x4){0.f, 0.f, 0.f, 0.f};

    const float SHIFT = 8.0f;   // log2-domain shift; softmax shift-invariant
    const int myq = q0 + wv * 16 + m16;
    const int psrow = (wv * 16 + m16) * 64;

    stage(0, 0);
    for (int kb = 0; kb <= qt; ++kb) {
        __syncthreads();                 // drains vmcnt -> stage(kb) visible to all
        int buf = kb & 1;
        if (kb < qt) stage(kb + 1, buf ^ 1);
        int kbase = kb * 64;
        bool diag = (kb == qt);

        // S^T = K Q^T : lane holds S[q=m16][key = kbase + nt*16 + quad*4 + r]
        #pragma unroll
        for (int nt = 0; nt < 4; nt++) {
            bf16x8 k0 = *(const bf16x8*)&KT[buf][0][(nt * 16 + m16) * 32 + colsw];
            bf16x8 k1 = *(const bf16x8*)&KT[buf][1][(nt * 16 + m16) * 32 + colsw];
            f32x4 zv = (f32x4){0.f, 0.f, 0.f, 0.f};
            zv = __builtin_amdgcn_mfma_f32_16x16x32_bf16(k0, aq0, zv, 0, 0, 0);
            zv = __builtin_amdgcn_mfma_f32_16x16x32_bf16(k1, aq1, zv, 0, 0, 0);

            bf16 t4[4] __attribute__((aligned(8)));
            #pragma unroll
            for (int r = 0; r < 4; r++) {
                float pv = exp2f(zv[r] - SHIFT);   // single v_exp_f32
                if (diag) {
                    int key = kbase + nt * 16 + quad * 4 + r;
                    if (key > myq) pv = 0.f;
                }
                t4[r] = __float2bfloat16(pv);
            }
            // keys nt*16+quad*4.. are chunk c = nt*2 + (quad>>1); XOR-swizzled slot
            int cw = (nt * 2 + (quad >> 1)) ^ psw;
            *(uint64_t*)&Ps[psrow + cw * 8 + (quad & 1) * 4] = *(const uint64_t*)t4;
        }

        // P fragments back (wave-private region, no barrier needed)
        int c0 = quad ^ psw;
        bf16x8 ap0 = *(const bf16x8*)&Ps[psrow + c0 * 8];
        bf16x8 ap1 = *(const bf16x8*)&Ps[psrow + (c0 ^ 4) * 8];

        // O += P V ; row sums ride the matrix pipe via the ones fragment
        __builtin_amdgcn_s_setprio(1);
        #pragma unroll
        for (int dt = 0; dt < 4; dt++) {
            bf16x8 v0 = *(const bf16x8*)&VT[buf][0][(dt * 16 + m16) * 32 + colsw];
            bf16x8 v1 = *(const bf16x8*)&VT[buf][1][(dt * 16 + m16) * 32 + colsw];
            o[dt] = __builtin_amdgcn_mfma_f32_16x16x32_bf16(ap0, v0, o[dt], 0, 0, 0);
            o[dt] = __builtin_amdgcn_mfma_f32_16x16x32_bf16(ap1, v1, o[dt], 0, 0, 0);
        }
        o_sum = __builtin_amdgcn_mfma_f32_16x16x32_bf16(ap0, bone, o_sum, 0, 0, 0);
        o_sum = __builtin_amdgcn_mfma_f32_16x16x32_bf16(ap1, bone, o_sum, 0, 0, 0);
        __builtin_amdgcn_s_setprio(0);
    }

    // epilogue: o_sum[r] is the row sum for q-row quad*4+r (same C-layout as o)
    #pragma unroll
    for (int r = 0; r < 4; r++) {
        float inv = 1.0f / o_sum[r];
        int rowg = q0 + wv * 16 + quad * 4 + r;
        #pragma unroll
        for (int dt = 0; dt < 4; dt++)
            Attn[(size_t)rowg * D_MODEL + hc + dt * 16 + m16] =
                __float2bfloat16(o[dt][r] * inv);
    }
}

extern "C" void kernel_launch(void* const* d_in, const int* in_sizes, int n_in,
                              void* d_out, int out_size, void* d_ws, size_t ws_size,
                              hipStream_t stream)
{
    const float* x  = (const float*)d_in[0];
    const int*   pos= (const int*)d_in[1];
    const float* Wq = (const float*)d_in[2];
    const float* Wk = (const float*)d_in[3];
    const float* Wv = (const float*)d_in[4];
    const float* Wo = (const float*)d_in[5];
    float* out = (float*)d_out;

    char* ws = (char*)d_ws;
    bf16*  xb   = (bf16*) (ws);                    // 8 MB
    bf16*  wqb  = (bf16*) (ws + ( 8ull << 20));    // 2 MB
    bf16*  wkb  = (bf16*) (ws + (10ull << 20));
    bf16*  wvb  = (bf16*) (ws + (12ull << 20));
    bf16*  wob  = (bf16*) (ws + (14ull << 20));
    float* Qf   = (float*)(ws + (16ull << 20));    // 16 MB
    float* Kf   = (float*)(ws + (32ull << 20));    // 16 MB
    bf16*  Qb   = (bf16*) (ws + (48ull << 20));    // 8 MB
    bf16*  Kb   = (bf16*) (ws + (56ull << 20));    // 8 MB
    bf16*  VtG  = (bf16*) (ws + (64ull << 20));    // 8 MB (V transposed [D][S])
    bf16*  Attn = (bf16*) (ws + (72ull << 20));    // 8 MB -> 80 MB total

    cvt_all<<<8192, 256, 0, stream>>>(x, Wq, Wk, Wv, Wo, xb, wqb, wkb, wvb, wob);

    qkv_gemm<<<dim3(8, 32, 3), 256, 0, stream>>>(xb, wqb, wkb, wvb, Qf, Kf, VtG);

    rope_kernel<<<2048, 256, 0, stream>>>(Qf, Kf, pos, Qb, Kb);

    attn_kernel<<<dim3(1024), 256, 0, stream>>>(Qb, Kb, VtG, Attn);

    out_gemm<<<dim3(8, 32), 256, 0, stream>>>(Attn, wob, out);
}

// Round 5
// 214.782 us; speedup vs baseline: 1.0484x; 1.0484x over previous
//
#include <hip/hip_runtime.h>
#include <hip/hip_bf16.h>
#include <stdint.h>
#include <math.h>

#define S_LEN   4096
#define D_MODEL 1024
#define NHEAD   16
#define DK      64

typedef __attribute__((ext_vector_type(8))) __bf16 bf16x8;
typedef __attribute__((ext_vector_type(4))) float  f32x4;
using bf16 = __hip_bfloat16;

__device__ __forceinline__ void load_lds16(const bf16* g, bf16* l) {
    __builtin_amdgcn_global_load_lds(
        (const __attribute__((address_space(1))) void*)g,
        (__attribute__((address_space(3))) void*)l, 16, 0, 0);
}

// ---------------- fused fp32 -> bf16 convert (x + 4 weights), 4 elems/thread ----------------
__global__ void cvt_all(const float* __restrict__ x,
                        const float* __restrict__ w0, const float* __restrict__ w1,
                        const float* __restrict__ w2, const float* __restrict__ w3,
                        bf16* __restrict__ xb,
                        bf16* __restrict__ b0, bf16* __restrict__ b1,
                        bf16* __restrict__ b2, bf16* __restrict__ b3)
{
    size_t i4 = ((size_t)blockIdx.x * 256 + threadIdx.x) * 4;
    const float* s; bf16* d; size_t off;
    const size_t NX = (size_t)S_LEN * D_MODEL;         // 4M
    const size_t NW = (size_t)D_MODEL * D_MODEL;       // 1M
    if (i4 < NX) { s = x; d = xb; off = i4; }
    else {
        size_t j = i4 - NX;
        int sel = (int)(j >> 20);
        off = j & (NW - 1);
        s = sel == 0 ? w0 : sel == 1 ? w1 : sel == 2 ? w2 : w3;
        d = sel == 0 ? b0 : sel == 1 ? b1 : sel == 2 ? b2 : b3;
    }
    float4 v = *(const float4*)&s[off];
    bf16 t[4] __attribute__((aligned(8)));
    t[0] = __float2bfloat16(v.x); t[1] = __float2bfloat16(v.y);
    t[2] = __float2bfloat16(v.z); t[3] = __float2bfloat16(v.w);
    *(uint64_t*)&d[off] = *(const uint64_t*)t;
}

// ---------------- QKV GEMM: C = Xb (4096x1024) * W^T ----------------
// z = 0 -> Qf (fp32), 1 -> Kf (fp32), 2 -> VtG (bf16, transposed [D][S])
__global__ __launch_bounds__(256) void qkv_gemm(
    const bf16* __restrict__ Xb,
    const bf16* __restrict__ Wq, const bf16* __restrict__ Wk, const bf16* __restrict__ Wv,
    float* __restrict__ Qf, float* __restrict__ Kf, bf16* __restrict__ VtG)
{
    const int K = D_MODEL, N = D_MODEL;
    int z = blockIdx.z;
    const bf16* B = (z == 0) ? Wq : (z == 1) ? Wk : Wv;

    __shared__ __align__(16) bf16 As[2][128 * 32];
    __shared__ __align__(16) bf16 Bs[2][128 * 32];
    __shared__ __align__(16) bf16 Ts[4][64 * 24];   // per-wave V-transpose strip

    int row0 = blockIdx.y * 128;
    int col0 = blockIdx.x * 128;
    int tid  = threadIdx.x;
    int wv   = tid >> 6, lane = tid & 63;
    int m16  = lane & 15, quad = lane >> 4;
    int wr   = (wv >> 1) * 64, wc = (wv & 1) * 64;
    int l4   = lane >> 2, l3 = (lane & 3) * 8;

    const bf16* ga_base = Xb + (size_t)(row0 + wv * 16 + l4) * K + l3;
    const bf16* gb_base = B  + (size_t)(col0 + wv * 16 + l4) * K + l3;

    auto stage = [&](int k0, int buf) {
        load_lds16(ga_base + k0,            &As[buf][wv * 512]);
        load_lds16(ga_base + k0 + 64 * K,   &As[buf][2048 + wv * 512]);
        load_lds16(gb_base + k0,            &Bs[buf][wv * 512]);
        load_lds16(gb_base + k0 + 64 * K,   &Bs[buf][2048 + wv * 512]);
    };

    f32x4 acc[4][4];
    #pragma unroll
    for (int i = 0; i < 4; i++)
        #pragma unroll
        for (int j = 0; j < 4; j++) acc[i][j] = (f32x4){0.f, 0.f, 0.f, 0.f};

    stage(0, 0);
    for (int k0 = 0; k0 < K; k0 += 32) {
        __syncthreads();
        int buf = (k0 >> 5) & 1;
        if (k0 + 32 < K) stage(k0 + 32, buf ^ 1);
        bf16x8 a[4], b[4];
        #pragma unroll
        for (int mi = 0; mi < 4; mi++) a[mi] = *(const bf16x8*)&As[buf][(wr + mi * 16 + m16) * 32 + quad * 8];
        #pragma unroll
        for (int ni = 0; ni < 4; ni++) b[ni] = *(const bf16x8*)&Bs[buf][(wc + ni * 16 + m16) * 32 + quad * 8];
        #pragma unroll
        for (int mi = 0; mi < 4; mi++)
            #pragma unroll
            for (int ni = 0; ni < 4; ni++)
                acc[mi][ni] = __builtin_amdgcn_mfma_f32_16x16x32_bf16(a[mi], b[ni], acc[mi][ni], 0, 0, 0);
    }

    if (z < 2) {
        float* O = (z == 0) ? Qf : Kf;
        #pragma unroll
        for (int mi = 0; mi < 4; mi++)
            #pragma unroll
            for (int ni = 0; ni < 4; ni++)
                #pragma unroll
                for (int r = 0; r < 4; r++) {
                    int gr = row0 + wr + mi * 16 + quad * 4 + r;
                    int gc = col0 + wc + ni * 16 + m16;
                    O[(size_t)gr * N + gc] = acc[mi][ni][r];
                }
    } else {
        // per-wave transpose through LDS, then coalesced 16B stores to VtG[gc][gr]
        #pragma unroll
        for (int mi = 0; mi < 4; mi++) {
            #pragma unroll
            for (int nt = 0; nt < 4; nt++) {
                bf16 t4[4] __attribute__((aligned(8)));
                #pragma unroll
                for (int r = 0; r < 4; r++) t4[r] = __float2bfloat16(acc[mi][nt][r]);
                *(uint64_t*)&Ts[wv][(nt * 16 + m16) * 24 + quad * 4] = *(const uint64_t*)t4;
            }
            #pragma unroll
            for (int rep = 0; rep < 2; rep++) {
                int c  = (lane >> 1) + rep * 32;
                int r8 = lane & 1;
                bf16x8 val = *(const bf16x8*)&Ts[wv][c * 24 + r8 * 8];
                int gc = col0 + wc + c;
                int gr = row0 + wr + mi * 16 + r8 * 8;
                *(bf16x8*)&VtG[(size_t)gc * S_LEN + gr] = val;
            }
        }
    }
}

// ---------------- Output GEMM: out = Attn(bf16) * Wo^T -> fp32 ----------------
__global__ __launch_bounds__(256) void out_gemm(
    const bf16* __restrict__ A_, const bf16* __restrict__ B,
    float* __restrict__ C)
{
    const int K = D_MODEL, N = D_MODEL;
    __shared__ __align__(16) bf16 As[2][128 * 32];
    __shared__ __align__(16) bf16 Bs[2][128 * 32];

    int row0 = blockIdx.y * 128;
    int col0 = blockIdx.x * 128;
    int tid  = threadIdx.x;
    int wv   = tid >> 6, lane = tid & 63;
    int m16  = lane & 15, quad = lane >> 4;
    int wr   = (wv >> 1) * 64, wc = (wv & 1) * 64;
    int l4   = lane >> 2, l3 = (lane & 3) * 8;

    const bf16* ga_base = A_ + (size_t)(row0 + wv * 16 + l4) * K + l3;
    const bf16* gb_base = B  + (size_t)(col0 + wv * 16 + l4) * K + l3;

    auto stage = [&](int k0, int buf) {
        load_lds16(ga_base + k0,            &As[buf][wv * 512]);
        load_lds16(ga_base + k0 + 64 * K,   &As[buf][2048 + wv * 512]);
        load_lds16(gb_base + k0,            &Bs[buf][wv * 512]);
        load_lds16(gb_base + k0 + 64 * K,   &Bs[buf][2048 + wv * 512]);
    };

    f32x4 acc[4][4];
    #pragma unroll
    for (int i = 0; i < 4; i++)
        #pragma unroll
        for (int j = 0; j < 4; j++) acc[i][j] = (f32x4){0.f, 0.f, 0.f, 0.f};

    stage(0, 0);
    for (int k0 = 0; k0 < K; k0 += 32) {
        __syncthreads();
        int buf = (k0 >> 5) & 1;
        if (k0 + 32 < K) stage(k0 + 32, buf ^ 1);
        bf16x8 a[4], b[4];
        #pragma unroll
        for (int mi = 0; mi < 4; mi++) a[mi] = *(const bf16x8*)&As[buf][(wr + mi * 16 + m16) * 32 + quad * 8];
        #pragma unroll
        for (int ni = 0; ni < 4; ni++) b[ni] = *(const bf16x8*)&Bs[buf][(wc + ni * 16 + m16) * 32 + quad * 8];
        #pragma unroll
        for (int mi = 0; mi < 4; mi++)
            #pragma unroll
            for (int ni = 0; ni < 4; ni++)
                acc[mi][ni] = __builtin_amdgcn_mfma_f32_16x16x32_bf16(a[mi], b[ni], acc[mi][ni], 0, 0, 0);
    }

    #pragma unroll
    for (int mi = 0; mi < 4; mi++)
        #pragma unroll
        for (int ni = 0; ni < 4; ni++)
            #pragma unroll
            for (int r = 0; r < 4; r++) {
                int gr = row0 + wr + mi * 16 + quad * 4 + r;
                int gc = col0 + wc + ni * 16 + m16;
                C[(size_t)gr * N + gc] = acc[mi][ni][r];
            }
}

// ---------------- RoPE (fp32 in, bf16 out) ----------------
// Folds (1/sqrt(dk)) * log2(e) into Q so attention can use exp2 directly
// (softmax over s*log2e in base 2 == softmax over s in base e, exactly).
__global__ void rope_kernel(const float* __restrict__ Qf, const float* __restrict__ Kf,
                            const int* __restrict__ pos,
                            bf16* __restrict__ Qb, bf16* __restrict__ Kb)
{
    int gid = blockIdx.x * 256 + threadIdx.x;
    size_t i8 = (size_t)gid * 8;
    int s   = (int)(i8 >> 10);
    int col = (int)(i8 & 1023);
    int pair0 = (col & 63) >> 1;          // 0..31, multiple of 4
    float p = (float)pos[s];

    float4 qa = *(const float4*)&Qf[i8];
    float4 qb_ = *(const float4*)&Qf[i8 + 4];
    float4 ka = *(const float4*)&Kf[i8];
    float4 kb_ = *(const float4*)&Kf[i8 + 4];
    float q[8] = {qa.x, qa.y, qa.z, qa.w, qb_.x, qb_.y, qb_.z, qb_.w};
    float k[8] = {ka.x, ka.y, ka.z, ka.w, kb_.x, kb_.y, kb_.z, kb_.w};

    bf16 oq[8] __attribute__((aligned(16)));
    bf16 ok[8] __attribute__((aligned(16)));
    const float scale = 0.18033688011112042f;   // (1/sqrt(64)) * log2(e)
    #pragma unroll
    for (int j = 0; j < 4; j++) {
        float fi = (float)(pair0 + j);
        // inv_freq = 10000^(-fi/32) = exp2(-fi * log2(10000)/32)
        float inv = exp2f(fi * (-0.41524101186092028f));
        float ang = p * inv;
        float sn, cs;
        __sincosf(ang, &sn, &cs);
        float q1 = q[2 * j], q2 = q[2 * j + 1];
        float k1 = k[2 * j], k2 = k[2 * j + 1];
        oq[2 * j]     = __float2bfloat16((q1 * cs - q2 * sn) * scale);
        oq[2 * j + 1] = __float2bfloat16((q1 * sn + q2 * cs) * scale);
        ok[2 * j]     = __float2bfloat16(k1 * cs - k2 * sn);
        ok[2 * j + 1] = __float2bfloat16(k1 * sn + k2 * cs);
    }
    *(bf16x8*)&Qb[i8] = *(const bf16x8*)oq;
    *(bf16x8*)&Kb[i8] = *(const bf16x8*)ok;
}

// ---------------- Flash attention: VALU-reduced softmax (fixed) ----------------
// Round-3 geometry (1024 blocks x 4 waves, 64-row q-tiles, 40960 B LDS ->
// 4 blocks/CU). Round-4 post-mortem: exp2f() lowered to __ocml_exp2_f32
// (range-check VALU bloat, VALUBusy 40->53%) and setprio hurt the 4-wave
// lockstep structure (m190). Fixes:
//  1. __builtin_amdgcn_exp2f = raw v_exp_f32 (1 op; log2e folded into RoPE
//     Q-scale so no pre-multiply). Exact: softmax shift/base invariant.
//  2. NO setprio (barrier-lockstep waves -> m190 negative case).
//  3. keep row sums on the MATRIX pipe: o_sum = mfma(P_frag, ones, o_sum)
//     (replaces 16 v_add/iter + epilogue shuffles; o_sum[r] is the row sum
//     in the same C-layout rows as o[dt][r]).
__global__ __launch_bounds__(256, 4) void attn_kernel(
    const bf16* __restrict__ Qb, const bf16* __restrict__ Kb, const bf16* __restrict__ VtG,
    bf16* __restrict__ Attn)
{
    int bx  = blockIdx.x;
    int h   = bx & 15;
    int qt  = 63 - (bx >> 4);            // longest q-tiles first
    int tid = threadIdx.x;
    int wv  = tid >> 6, lane = tid & 63;
    int m16 = lane & 15, quad = lane >> 4;
    int csw   = (lane & 3) ^ ((lane >> 3) & 3);     // staging column permutation
    int colsw = ((quad ^ ((m16 >> 1) & 3)) << 3);   // matching read-side XOR (elements)
    int psw   = (m16 & 7) ^ ((m16 >> 3) & 1);       // Ps chunk swizzle for this row
    int hc  = h * DK;
    int q0  = qt * 64;

    __shared__ __align__(16) bf16 KT[2][2][64 * 32];  // [buf][d-half][key*32 + d(swz)]   16 KB
    __shared__ __align__(16) bf16 VT[2][2][64 * 32];  // [buf][key-half][d*32 + key(swz)] 16 KB
    __shared__ __align__(16) bf16 Ps[64 * 64];        // XOR-swizzled P                    8 KB

    // staging: 256 threads cover a full 64x32 half-tile per load (1 op each)
    const bf16* kgl = Kb  + (size_t)(wv * 16 + (lane >> 2)) * D_MODEL + hc + csw * 8;
    const bf16* vgl = VtG + (size_t)(hc + wv * 16 + (lane >> 2)) * S_LEN + csw * 8;

    auto stage = [&](int kb, int buf) {
        size_t ko = (size_t)kb * 64;
        load_lds16(kgl + ko * D_MODEL,       &KT[buf][0][wv * 512]);
        load_lds16(kgl + ko * D_MODEL + 32,  &KT[buf][1][wv * 512]);
        load_lds16(vgl + ko,                 &VT[buf][0][wv * 512]);
        load_lds16(vgl + ko + 32,            &VT[buf][1][wv * 512]);
    };

    // Q fragment for this wave's 16 rows, in registers for the whole loop
    const bf16* qp = Qb + (size_t)(q0 + wv * 16 + m16) * D_MODEL + hc;
    bf16x8 aq0 = *(const bf16x8*)&qp[quad * 8];
    bf16x8 aq1 = *(const bf16x8*)&qp[32 + quad * 8];

    // constant all-ones B fragment for the row-sum MFMA
    bf16x8 bone;
    #pragma unroll
    for (int j = 0; j < 8; j++) bone[j] = (__bf16)1.0f;

    f32x4 o[4];
    f32x4 o_sum = (f32x4){0.f, 0.f, 0.f, 0.f};
    #pragma unroll
    for (int dt = 0; dt < 4; dt++) o[dt] = (f32x4){0.f, 0.f, 0.f, 0.f};

    const float SHIFT = 8.0f;   // log2-domain shift; softmax shift-invariant
    const int myq = q0 + wv * 16 + m16;
    const int psrow = (wv * 16 + m16) * 64;

    stage(0, 0);
    for (int kb = 0; kb <= qt; ++kb) {
        __syncthreads();                 // drains vmcnt -> stage(kb) visible to all
        int buf = kb & 1;
        if (kb < qt) stage(kb + 1, buf ^ 1);
        int kbase = kb * 64;
        bool diag = (kb == qt);

        // S^T = K Q^T : lane holds S[q=m16][key = kbase + nt*16 + quad*4 + r]
        #pragma unroll
        for (int nt = 0; nt < 4; nt++) {
            bf16x8 k0 = *(const bf16x8*)&KT[buf][0][(nt * 16 + m16) * 32 + colsw];
            bf16x8 k1 = *(const bf16x8*)&KT[buf][1][(nt * 16 + m16) * 32 + colsw];
            f32x4 zv = (f32x4){0.f, 0.f, 0.f, 0.f};
            zv = __builtin_amdgcn_mfma_f32_16x16x32_bf16(k0, aq0, zv, 0, 0, 0);
            zv = __builtin_amdgcn_mfma_f32_16x16x32_bf16(k1, aq1, zv, 0, 0, 0);

            bf16 t4[4] __attribute__((aligned(8)));
            #pragma unroll
            for (int r = 0; r < 4; r++) {
                float pv = __builtin_amdgcn_exp2f(zv[r] - SHIFT);   // raw v_exp_f32
                if (diag) {
                    int key = kbase + nt * 16 + quad * 4 + r;
                    if (key > myq) pv = 0.f;
                }
                t4[r] = __float2bfloat16(pv);
            }
            // keys nt*16+quad*4.. are chunk c = nt*2 + (quad>>1); XOR-swizzled slot
            int cw = (nt * 2 + (quad >> 1)) ^ psw;
            *(uint64_t*)&Ps[psrow + cw * 8 + (quad & 1) * 4] = *(const uint64_t*)t4;
        }

        // P fragments back (wave-private region, no barrier needed)
        int c0 = quad ^ psw;
        bf16x8 ap0 = *(const bf16x8*)&Ps[psrow + c0 * 8];
        bf16x8 ap1 = *(const bf16x8*)&Ps[psrow + (c0 ^ 4) * 8];

        // O += P V ; row sums ride the matrix pipe via the ones fragment
        #pragma unroll
        for (int dt = 0; dt < 4; dt++) {
            bf16x8 v0 = *(const bf16x8*)&VT[buf][0][(dt * 16 + m16) * 32 + colsw];
            bf16x8 v1 = *(const bf16x8*)&VT[buf][1][(dt * 16 + m16) * 32 + colsw];
            o[dt] = __builtin_amdgcn_mfma_f32_16x16x32_bf16(ap0, v0, o[dt], 0, 0, 0);
            o[dt] = __builtin_amdgcn_mfma_f32_16x16x32_bf16(ap1, v1, o[dt], 0, 0, 0);
        }
        o_sum = __builtin_amdgcn_mfma_f32_16x16x32_bf16(ap0, bone, o_sum, 0, 0, 0);
        o_sum = __builtin_amdgcn_mfma_f32_16x16x32_bf16(ap1, bone, o_sum, 0, 0, 0);
    }

    // epilogue: o_sum[r] is the row sum for q-row quad*4+r (same C-layout as o)
    #pragma unroll
    for (int r = 0; r < 4; r++) {
        float inv = 1.0f / o_sum[r];
        int rowg = q0 + wv * 16 + quad * 4 + r;
        #pragma unroll
        for (int dt = 0; dt < 4; dt++)
            Attn[(size_t)rowg * D_MODEL + hc + dt * 16 + m16] =
                __float2bfloat16(o[dt][r] * inv);
    }
}

extern "C" void kernel_launch(void* const* d_in, const int* in_sizes, int n_in,
                              void* d_out, int out_size, void* d_ws, size_t ws_size,
                              hipStream_t stream)
{
    const float* x  = (const float*)d_in[0];
    const int*   pos= (const int*)d_in[1];
    const float* Wq = (const float*)d_in[2];
    const float* Wk = (const float*)d_in[3];
    const float* Wv = (const float*)d_in[4];
    const float* Wo = (const float*)d_in[5];
    float* out = (float*)d_out;

    char* ws = (char*)d_ws;
    bf16*  xb   = (bf16*) (ws);                    // 8 MB
    bf16*  wqb  = (bf16*) (ws + ( 8ull << 20));    // 2 MB
    bf16*  wkb  = (bf16*) (ws + (10ull << 20));
    bf16*  wvb  = (bf16*) (ws + (12ull << 20));
    bf16*  wob  = (bf16*) (ws + (14ull << 20));
    float* Qf   = (float*)(ws + (16ull << 20));    // 16 MB
    float* Kf   = (float*)(ws + (32ull << 20));    // 16 MB
    bf16*  Qb   = (bf16*) (ws + (48ull << 20));    // 8 MB
    bf16*  Kb   = (bf16*) (ws + (56ull << 20));    // 8 MB
    bf16*  VtG  = (bf16*) (ws + (64ull << 20));    // 8 MB (V transposed [D][S])
    bf16*  Attn = (bf16*) (ws + (72ull << 20));    // 8 MB -> 80 MB total

    cvt_all<<<8192, 256, 0, stream>>>(x, Wq, Wk, Wv, Wo, xb, wqb, wkb, wvb, wob);

    qkv_gemm<<<dim3(8, 32, 3), 256, 0, stream>>>(xb, wqb, wkb, wvb, Qf, Kf, VtG);

    rope_kernel<<<2048, 256, 0, stream>>>(Qf, Kf, pos, Qb, Kb);

    attn_kernel<<<dim3(1024), 256, 0, stream>>>(Qb, Kb, VtG, Attn);

    out_gemm<<<dim3(8, 32), 256, 0, stream>>>(Attn, wob, out);
}

// Round 6
// 210.876 us; speedup vs baseline: 1.0678x; 1.0185x over previous
//
#include <hip/hip_runtime.h>
#include <hip/hip_bf16.h>
#include <stdint.h>
#include <math.h>

#define S_LEN   4096
#define D_MODEL 1024
#define NHEAD   16
#define DK      64

typedef __attribute__((ext_vector_type(8))) __bf16 bf16x8;
typedef __attribute__((ext_vector_type(4))) float  f32x4;
using bf16 = __hip_bfloat16;

__device__ __forceinline__ void load_lds16(const bf16* g, bf16* l) {
    __builtin_amdgcn_global_load_lds(
        (const __attribute__((address_space(1))) void*)g,
        (__attribute__((address_space(3))) void*)l, 16, 0, 0);
}

// ---------------- fused fp32 -> bf16 convert (x + 4 weights), 4 elems/thread ----------------
__global__ void cvt_all(const float* __restrict__ x,
                        const float* __restrict__ w0, const float* __restrict__ w1,
                        const float* __restrict__ w2, const float* __restrict__ w3,
                        bf16* __restrict__ xb,
                        bf16* __restrict__ b0, bf16* __restrict__ b1,
                        bf16* __restrict__ b2, bf16* __restrict__ b3)
{
    size_t i4 = ((size_t)blockIdx.x * 256 + threadIdx.x) * 4;
    const float* s; bf16* d; size_t off;
    const size_t NX = (size_t)S_LEN * D_MODEL;         // 4M
    const size_t NW = (size_t)D_MODEL * D_MODEL;       // 1M
    if (i4 < NX) { s = x; d = xb; off = i4; }
    else {
        size_t j = i4 - NX;
        int sel = (int)(j >> 20);
        off = j & (NW - 1);
        s = sel == 0 ? w0 : sel == 1 ? w1 : sel == 2 ? w2 : w3;
        d = sel == 0 ? b0 : sel == 1 ? b1 : sel == 2 ? b2 : b3;
    }
    float4 v = *(const float4*)&s[off];
    bf16 t[4] __attribute__((aligned(8)));
    t[0] = __float2bfloat16(v.x); t[1] = __float2bfloat16(v.y);
    t[2] = __float2bfloat16(v.z); t[3] = __float2bfloat16(v.w);
    *(uint64_t*)&d[off] = *(const uint64_t*)t;
}

// ---------------- QKV GEMM with fused RoPE epilogue ----------------
// z = 0 -> Qb (bf16, roped, scaled by (1/8)*log2e), 1 -> Kb (bf16, roped),
// 2 -> VtG (bf16, transposed [D][S]).
// RoPE in epilogue: pair partner (col gc^1) lives in lane^1 -> __shfl_xor(x,1)
// (DPP quad-perm). Math identical to the old fp32 Qf/Kf + rope_kernel path
// (fp32 acc -> fp32 rotate -> bf16); saves 64 MB HBM traffic + a launch.
__global__ __launch_bounds__(256) void qkv_gemm(
    const bf16* __restrict__ Xb,
    const bf16* __restrict__ Wq, const bf16* __restrict__ Wk, const bf16* __restrict__ Wv,
    const int* __restrict__ pos,
    bf16* __restrict__ Qb, bf16* __restrict__ Kb, bf16* __restrict__ VtG)
{
    const int K = D_MODEL, N = D_MODEL;
    int z = blockIdx.z;
    const bf16* B = (z == 0) ? Wq : (z == 1) ? Wk : Wv;

    __shared__ __align__(16) bf16 As[2][128 * 32];
    __shared__ __align__(16) bf16 Bs[2][128 * 32];
    __shared__ __align__(16) bf16 Ts[4][64 * 24];   // per-wave V-transpose strip (z=2)

    int row0 = blockIdx.y * 128;
    int col0 = blockIdx.x * 128;
    int tid  = threadIdx.x;
    int wv   = tid >> 6, lane = tid & 63;
    int m16  = lane & 15, quad = lane >> 4;
    int wr   = (wv >> 1) * 64, wc = (wv & 1) * 64;
    int l4   = lane >> 2, l3 = (lane & 3) * 8;

    const bf16* ga_base = Xb + (size_t)(row0 + wv * 16 + l4) * K + l3;
    const bf16* gb_base = B  + (size_t)(col0 + wv * 16 + l4) * K + l3;

    auto stage = [&](int k0, int buf) {
        load_lds16(ga_base + k0,            &As[buf][wv * 512]);
        load_lds16(ga_base + k0 + 64 * K,   &As[buf][2048 + wv * 512]);
        load_lds16(gb_base + k0,            &Bs[buf][wv * 512]);
        load_lds16(gb_base + k0 + 64 * K,   &Bs[buf][2048 + wv * 512]);
    };

    f32x4 acc[4][4];
    #pragma unroll
    for (int i = 0; i < 4; i++)
        #pragma unroll
        for (int j = 0; j < 4; j++) acc[i][j] = (f32x4){0.f, 0.f, 0.f, 0.f};

    stage(0, 0);
    for (int k0 = 0; k0 < K; k0 += 32) {
        __syncthreads();
        int buf = (k0 >> 5) & 1;
        if (k0 + 32 < K) stage(k0 + 32, buf ^ 1);
        bf16x8 a[4], b[4];
        #pragma unroll
        for (int mi = 0; mi < 4; mi++) a[mi] = *(const bf16x8*)&As[buf][(wr + mi * 16 + m16) * 32 + quad * 8];
        #pragma unroll
        for (int ni = 0; ni < 4; ni++) b[ni] = *(const bf16x8*)&Bs[buf][(wc + ni * 16 + m16) * 32 + quad * 8];
        #pragma unroll
        for (int mi = 0; mi < 4; mi++)
            #pragma unroll
            for (int ni = 0; ni < 4; ni++)
                acc[mi][ni] = __builtin_amdgcn_mfma_f32_16x16x32_bf16(a[mi], b[ni], acc[mi][ni], 0, 0, 0);
    }

    if (z < 2) {
        // fused RoPE -> bf16 (Q additionally scaled by (1/sqrt(64))*log2(e)
        // so attention can use raw v_exp_f32 in base 2)
        bf16* O = (z == 0) ? Qb : Kb;
        const float qscale = (z == 0) ? 0.18033688011112042f : 1.0f;
        // pair index = ((gc & 63) >> 1); with 128-col tiles aligned to 64-d heads:
        // gc & 63 = ni*16 + m16
        float invf[4];
        #pragma unroll
        for (int ni = 0; ni < 4; ni++) {
            float fi = (float)((ni * 16 + m16) >> 1);
            invf[ni] = exp2f(fi * (-0.41524101186092028f));  // 10000^(-fi/32)
        }
        bool odd = (m16 & 1) != 0;
        #pragma unroll
        for (int mi = 0; mi < 4; mi++) {
            #pragma unroll
            for (int r = 0; r < 4; r++) {
                int gr = row0 + wr + mi * 16 + quad * 4 + r;
                float p = (float)pos[gr];
                #pragma unroll
                for (int ni = 0; ni < 4; ni++) {
                    float own   = acc[mi][ni][r];
                    float other = __shfl_xor(own, 1);   // col gc^1 partner
                    float sn, cs;
                    __sincosf(p * invf[ni], &sn, &cs);
                    float x1 = odd ? other : own;
                    float x2 = odd ? own   : other;
                    float res = odd ? (x1 * sn + x2 * cs) : (x1 * cs - x2 * sn);
                    int gc = col0 + wc + ni * 16 + m16;
                    O[(size_t)gr * N + gc] = __float2bfloat16(res * qscale);
                }
            }
        }
    } else {
        // per-wave transpose through LDS, then coalesced 16B stores to VtG[gc][gr]
        #pragma unroll
        for (int mi = 0; mi < 4; mi++) {
            #pragma unroll
            for (int nt = 0; nt < 4; nt++) {
                bf16 t4[4] __attribute__((aligned(8)));
                #pragma unroll
                for (int r = 0; r < 4; r++) t4[r] = __float2bfloat16(acc[mi][nt][r]);
                *(uint64_t*)&Ts[wv][(nt * 16 + m16) * 24 + quad * 4] = *(const uint64_t*)t4;
            }
            #pragma unroll
            for (int rep = 0; rep < 2; rep++) {
                int c  = (lane >> 1) + rep * 32;
                int r8 = lane & 1;
                bf16x8 val = *(const bf16x8*)&Ts[wv][c * 24 + r8 * 8];
                int gc = col0 + wc + c;
                int gr = row0 + wr + mi * 16 + r8 * 8;
                *(bf16x8*)&VtG[(size_t)gc * S_LEN + gr] = val;
            }
        }
    }
}

// ---------------- Output GEMM: out = Attn(bf16) * Wo^T -> fp32 ----------------
// 128x64 tiles -> grid (16,32) = 512 blocks = 2 blocks/CU (was 256 = 1/CU,
// latency-starved: 1 wave/SIMD in a 2-barrier-per-K-step loop).
__global__ __launch_bounds__(256) void out_gemm(
    const bf16* __restrict__ A_, const bf16* __restrict__ B,
    float* __restrict__ C)
{
    const int K = D_MODEL, N = D_MODEL;
    __shared__ __align__(16) bf16 As[2][128 * 32];   // 16 KB
    __shared__ __align__(16) bf16 Bs[2][64 * 32];    //  8 KB

    int row0 = blockIdx.y * 128;
    int col0 = blockIdx.x * 64;
    int tid  = threadIdx.x;
    int wv   = tid >> 6, lane = tid & 63;
    int m16  = lane & 15, quad = lane >> 4;
    int wr   = (wv >> 1) * 64, wc = (wv & 1) * 32;   // 2x2 waves of 64x32
    int l4   = lane >> 2, l3 = (lane & 3) * 8;

    const bf16* ga_base = A_ + (size_t)(row0 + wv * 16 + l4) * K + l3;
    const bf16* gb_base = B  + (size_t)(col0 + wv * 16 + l4) * K + l3;  // rows 0..63

    auto stage = [&](int k0, int buf) {
        load_lds16(ga_base + k0,            &As[buf][wv * 512]);
        load_lds16(ga_base + k0 + 64 * K,   &As[buf][2048 + wv * 512]);
        load_lds16(gb_base + k0,            &Bs[buf][wv * 512]);
    };

    f32x4 acc[4][2];
    #pragma unroll
    for (int i = 0; i < 4; i++)
        #pragma unroll
        for (int j = 0; j < 2; j++) acc[i][j] = (f32x4){0.f, 0.f, 0.f, 0.f};

    stage(0, 0);
    for (int k0 = 0; k0 < K; k0 += 32) {
        __syncthreads();
        int buf = (k0 >> 5) & 1;
        if (k0 + 32 < K) stage(k0 + 32, buf ^ 1);
        bf16x8 a[4], b[2];
        #pragma unroll
        for (int mi = 0; mi < 4; mi++) a[mi] = *(const bf16x8*)&As[buf][(wr + mi * 16 + m16) * 32 + quad * 8];
        #pragma unroll
        for (int ni = 0; ni < 2; ni++) b[ni] = *(const bf16x8*)&Bs[buf][(wc + ni * 16 + m16) * 32 + quad * 8];
        #pragma unroll
        for (int mi = 0; mi < 4; mi++)
            #pragma unroll
            for (int ni = 0; ni < 2; ni++)
                acc[mi][ni] = __builtin_amdgcn_mfma_f32_16x16x32_bf16(a[mi], b[ni], acc[mi][ni], 0, 0, 0);
    }

    #pragma unroll
    for (int mi = 0; mi < 4; mi++)
        #pragma unroll
        for (int ni = 0; ni < 2; ni++)
            #pragma unroll
            for (int r = 0; r < 4; r++) {
                int gr = row0 + wr + mi * 16 + quad * 4 + r;
                int gc = col0 + wc + ni * 16 + m16;
                C[(size_t)gr * N + gc] = acc[mi][ni][r];
            }
}

// ---------------- Flash attention (unchanged from round 5) ----------------
// 1024 blocks x 4 waves, 64-row q-tiles, 40960 B LDS -> 4 blocks/CU.
// Conflict-free staged KT/VT (both-sides XOR swizzle), swapped QK^T with
// packed-b64 Ps writes, raw v_exp_f32 softmax (log2e folded into Qb),
// row sums on the matrix pipe via ones-MFMA.
__global__ __launch_bounds__(256, 4) void attn_kernel(
    const bf16* __restrict__ Qb, const bf16* __restrict__ Kb, const bf16* __restrict__ VtG,
    bf16* __restrict__ Attn)
{
    int bx  = blockIdx.x;
    int h   = bx & 15;
    int qt  = 63 - (bx >> 4);            // longest q-tiles first
    int tid = threadIdx.x;
    int wv  = tid >> 6, lane = tid & 63;
    int m16 = lane & 15, quad = lane >> 4;
    int csw   = (lane & 3) ^ ((lane >> 3) & 3);     // staging column permutation
    int colsw = ((quad ^ ((m16 >> 1) & 3)) << 3);   // matching read-side XOR (elements)
    int psw   = (m16 & 7) ^ ((m16 >> 3) & 1);       // Ps chunk swizzle for this row
    int hc  = h * DK;
    int q0  = qt * 64;

    __shared__ __align__(16) bf16 KT[2][2][64 * 32];  // [buf][d-half][key*32 + d(swz)]   16 KB
    __shared__ __align__(16) bf16 VT[2][2][64 * 32];  // [buf][key-half][d*32 + key(swz)] 16 KB
    __shared__ __align__(16) bf16 Ps[64 * 64];        // XOR-swizzled P                    8 KB

    // staging: 256 threads cover a full 64x32 half-tile per load (1 op each)
    const bf16* kgl = Kb  + (size_t)(wv * 16 + (lane >> 2)) * D_MODEL + hc + csw * 8;
    const bf16* vgl = VtG + (size_t)(hc + wv * 16 + (lane >> 2)) * S_LEN + csw * 8;

    auto stage = [&](int kb, int buf) {
        size_t ko = (size_t)kb * 64;
        load_lds16(kgl + ko * D_MODEL,       &KT[buf][0][wv * 512]);
        load_lds16(kgl + ko * D_MODEL + 32,  &KT[buf][1][wv * 512]);
        load_lds16(vgl + ko,                 &VT[buf][0][wv * 512]);
        load_lds16(vgl + ko + 32,            &VT[buf][1][wv * 512]);
    };

    // Q fragment for this wave's 16 rows, in registers for the whole loop
    const bf16* qp = Qb + (size_t)(q0 + wv * 16 + m16) * D_MODEL + hc;
    bf16x8 aq0 = *(const bf16x8*)&qp[quad * 8];
    bf16x8 aq1 = *(const bf16x8*)&qp[32 + quad * 8];

    // constant all-ones B fragment for the row-sum MFMA
    bf16x8 bone;
    #pragma unroll
    for (int j = 0; j < 8; j++) bone[j] = (__bf16)1.0f;

    f32x4 o[4];
    f32x4 o_sum = (f32x4){0.f, 0.f, 0.f, 0.f};
    #pragma unroll
    for (int dt = 0; dt < 4; dt++) o[dt] = (f32x4){0.f, 0.f, 0.f, 0.f};

    const float SHIFT = 8.0f;   // log2-domain shift; softmax shift-invariant
    const int myq = q0 + wv * 16 + m16;
    const int psrow = (wv * 16 + m16) * 64;

    stage(0, 0);
    for (int kb = 0; kb <= qt; ++kb) {
        __syncthreads();                 // drains vmcnt -> stage(kb) visible to all
        int buf = kb & 1;
        if (kb < qt) stage(kb + 1, buf ^ 1);
        int kbase = kb * 64;
        bool diag = (kb == qt);

        // S^T = K Q^T : lane holds S[q=m16][key = kbase + nt*16 + quad*4 + r]
        #pragma unroll
        for (int nt = 0; nt < 4; nt++) {
            bf16x8 k0 = *(const bf16x8*)&KT[buf][0][(nt * 16 + m16) * 32 + colsw];
            bf16x8 k1 = *(const bf16x8*)&KT[buf][1][(nt * 16 + m16) * 32 + colsw];
            f32x4 zv = (f32x4){0.f, 0.f, 0.f, 0.f};
            zv = __builtin_amdgcn_mfma_f32_16x16x32_bf16(k0, aq0, zv, 0, 0, 0);
            zv = __builtin_amdgcn_mfma_f32_16x16x32_bf16(k1, aq1, zv, 0, 0, 0);

            bf16 t4[4] __attribute__((aligned(8)));
            #pragma unroll
            for (int r = 0; r < 4; r++) {
                float pv = __builtin_amdgcn_exp2f(zv[r] - SHIFT);   // raw v_exp_f32
                if (diag) {
                    int key = kbase + nt * 16 + quad * 4 + r;
                    if (key > myq) pv = 0.f;
                }
                t4[r] = __float2bfloat16(pv);
            }
            // keys nt*16+quad*4.. are chunk c = nt*2 + (quad>>1); XOR-swizzled slot
            int cw = (nt * 2 + (quad >> 1)) ^ psw;
            *(uint64_t*)&Ps[psrow + cw * 8 + (quad & 1) * 4] = *(const uint64_t*)t4;
        }

        // P fragments back (wave-private region, no barrier needed)
        int c0 = quad ^ psw;
        bf16x8 ap0 = *(const bf16x8*)&Ps[psrow + c0 * 8];
        bf16x8 ap1 = *(const bf16x8*)&Ps[psrow + (c0 ^ 4) * 8];

        // O += P V ; row sums ride the matrix pipe via the ones fragment
        #pragma unroll
        for (int dt = 0; dt < 4; dt++) {
            bf16x8 v0 = *(const bf16x8*)&VT[buf][0][(dt * 16 + m16) * 32 + colsw];
            bf16x8 v1 = *(const bf16x8*)&VT[buf][1][(dt * 16 + m16) * 32 + colsw];
            o[dt] = __builtin_amdgcn_mfma_f32_16x16x32_bf16(ap0, v0, o[dt], 0, 0, 0);
            o[dt] = __builtin_amdgcn_mfma_f32_16x16x32_bf16(ap1, v1, o[dt], 0, 0, 0);
        }
        o_sum = __builtin_amdgcn_mfma_f32_16x16x32_bf16(ap0, bone, o_sum, 0, 0, 0);
        o_sum = __builtin_amdgcn_mfma_f32_16x16x32_bf16(ap1, bone, o_sum, 0, 0, 0);
    }

    // epilogue: o_sum[r] is the row sum for q-row quad*4+r (same C-layout as o)
    #pragma unroll
    for (int r = 0; r < 4; r++) {
        float inv = 1.0f / o_sum[r];
        int rowg = q0 + wv * 16 + quad * 4 + r;
        #pragma unroll
        for (int dt = 0; dt < 4; dt++)
            Attn[(size_t)rowg * D_MODEL + hc + dt * 16 + m16] =
                __float2bfloat16(o[dt][r] * inv);
    }
}

extern "C" void kernel_launch(void* const* d_in, const int* in_sizes, int n_in,
                              void* d_out, int out_size, void* d_ws, size_t ws_size,
                              hipStream_t stream)
{
    const float* x  = (const float*)d_in[0];
    const int*   pos= (const int*)d_in[1];
    const float* Wq = (const float*)d_in[2];
    const float* Wk = (const float*)d_in[3];
    const float* Wv = (const float*)d_in[4];
    const float* Wo = (const float*)d_in[5];
    float* out = (float*)d_out;

    char* ws = (char*)d_ws;
    bf16*  xb   = (bf16*) (ws);                    // 8 MB
    bf16*  wqb  = (bf16*) (ws + ( 8ull << 20));    // 2 MB
    bf16*  wkb  = (bf16*) (ws + (10ull << 20));
    bf16*  wvb  = (bf16*) (ws + (12ull << 20));
    bf16*  wob  = (bf16*) (ws + (14ull << 20));
    bf16*  Qb   = (bf16*) (ws + (16ull << 20));    // 8 MB (roped, scaled)
    bf16*  Kb   = (bf16*) (ws + (24ull << 20));    // 8 MB (roped)
    bf16*  VtG  = (bf16*) (ws + (32ull << 20));    // 8 MB (V transposed [D][S])
    bf16*  Attn = (bf16*) (ws + (40ull << 20));    // 8 MB -> 48 MB total

    cvt_all<<<8192, 256, 0, stream>>>(x, Wq, Wk, Wv, Wo, xb, wqb, wkb, wvb, wob);

    qkv_gemm<<<dim3(8, 32, 3), 256, 0, stream>>>(xb, wqb, wkb, wvb, pos, Qb, Kb, VtG);

    attn_kernel<<<dim3(1024), 256, 0, stream>>>(Qb, Kb, VtG, Attn);

    out_gemm<<<dim3(16, 32), 256, 0, stream>>>(Attn, wob, out);
}